// Round 12
// baseline (256.477 us; speedup 1.0000x reference)
//
#include <hip/hip_runtime.h>
#include <hip/hip_bf16.h>
#include <stdint.h>

#define KD 512
#define OD 8
#define SZ (KD*KD*OD)       // 2097152 elements per tensor (A,B,C)
#define PLANE (KD*KD)       // 262144

typedef short v8s __attribute__((ext_vector_type(8)));
typedef float v4f __attribute__((ext_vector_type(4)));

#define GLOBAL_AS __attribute__((address_space(1)))
#define LDS_AS __attribute__((address_space(3)))

static __device__ __forceinline__ unsigned short f2bf(float f) {
    union { float f; unsigned int u; } v; v.f = f;
    unsigned int u = v.u;
    unsigned int r = u + 0x7FFF + ((u >> 16) & 1);   // RNE
    return (unsigned short)(r >> 16);
}

static __device__ __forceinline__ void async16(const unsigned short* g, unsigned short* l) {
    __builtin_amdgcn_global_load_lds((const GLOBAL_AS void*)g, (LDS_AS void*)l, 16, 0, 0);
}

static __device__ __forceinline__ void bar() {
    __builtin_amdgcn_sched_barrier(0);
    __builtin_amdgcn_s_barrier();
    __builtin_amdgcn_sched_barrier(0);
}

// ---------------------------------------------------------------------------
// FRAGMENT LAYOUT v2 (k-major, verified R6-R11): fragment (16 rows x 32 k)
// = 512 contiguous elems (1 KB):
//   elem_off = p*PLANE + (k>>5)*16384 + (r>>4)*512
//            + ((k>>3)&3)*128 + (r&15)*8 + (k&7)
// lane l owns elems [l*8, l*8+8) — the mfma_f32_16x16x32_bf16 operand map.
// ---------------------------------------------------------------------------

// ---------------------------------------------------------------------------
// Pack (R9 verbatim, passed 3x): A-pack emits full 1 KB fragment lines;
// B-pack transposes through swizzled LDS.  block 0 zeroes probs_acc.
// ---------------------------------------------------------------------------
__global__ __launch_bounds__(256) void pack_kernel(const float* __restrict__ yp,
                                                   unsigned short* __restrict__ Wbf,
                                                   unsigned short* __restrict__ Xbf,
                                                   float* __restrict__ probs_acc) {
    __shared__ unsigned short lds[8192];
    const float* Pa = yp;
    const float* Pb = yp + KD;
    const float* Pc = yp + 2 * KD;
    const float* A  = yp + 3 * KD;
    const float* B  = A + SZ;
    const int b = blockIdx.x;
    const int t = threadIdx.x;

    if (b == 0) { probs_acc[t] = 0.0f; probs_acc[t + 256] = 0.0f; }

    if (b < 256) {
        // ---- A-pack: jt = b>>3 (16 j), kb = b&7 (64 k) ----
        const int jt = b >> 3, kb = b & 7;
        const int j0 = jt * 16, k0 = kb * 64;
        #pragma unroll
        for (int cc = 0; cc < 2; ++cc) {
            const int cell = cc * 256 + t;
            const int kl = (cell & 31) * 2;
            const int jl = cell >> 5;
            const int j = j0 + jl, k = k0 + kl;
            const float pb = Pb[j];
            const float s0 = pb * Pc[k];
            const float s1 = pb * Pc[k + 1];
            const float4* src = (const float4*)(A + ((size_t)j * KD + k) * 8);
            float av[16];
            ((float4*)av)[0] = src[0];
            ((float4*)av)[1] = src[1];
            ((float4*)av)[2] = src[2];
            ((float4*)av)[3] = src[3];
            const int swz = (jl & 7) << 3;
            #pragma unroll
            for (int x = 0; x < 8; ++x) {
                ushort2 wv;
                wv.x = f2bf(av[x] * s0);
                wv.y = f2bf(av[8 + x] * s1);
                *(ushort2*)&lds[jl * 512 + x * 64 + (kl ^ swz)] = wv;
            }
        }
        __syncthreads();
        #pragma unroll
        for (int ss = 0; ss < 4; ++ss) {
            const int slot = ss * 256 + t;
            const int x = slot >> 7;
            const int kcc = (slot >> 6) & 1;
            const int l = slot & 63;
            const int jl = l & 15, kq = l >> 4;
            const int klocal = kcc * 32 + kq * 8;
            const int swz = (jl & 7) << 3;
            uint4 v = *(const uint4*)&lds[jl * 512 + x * 64 + (klocal ^ swz)];
            const size_t fo = (size_t)(kb * 2 + kcc) * 16384 + (size_t)jt * 512 + l * 8;
            *(uint4*)(Wbf + (size_t)x * PLANE + fo) = v;
        }
    } else {
        // ---- B-pack ----
        const int tb = b - 256;
        const int k0 = (tb / 16) * 32;
        const int i0 = (tb % 16) * 32;
        char* ldsb = (char*)lds;
        #pragma unroll
        for (int p = 0; p < 4; ++p) {
            const int idx = t + p * 256;
            const int dk = idx >> 5;
            const int di = idx & 31;
            const float pa = Pa[i0 + di];
            const float4* src = (const float4*)(B + ((size_t)(k0 + dk) * KD + (i0 + di)) * 8);
            float bv[8];
            ((float4*)bv)[0] = src[0];
            ((float4*)bv)[1] = src[1];
            const int swz = (di & 7) << 4;
            #pragma unroll
            for (int y = 0; y < 8; ++y)
                *(unsigned short*)(ldsb + (y * 32 + di) * 64 + ((dk * 2) ^ swz)) =
                    f2bf(bv[y] * pa);
        }
        __syncthreads();
        #pragma unroll
        for (int p = 0; p < 4; ++p) {
            const int c = t + p * 256;
            const int y = c >> 7;
            const int rem = c & 127;
            const int di = rem >> 2;
            const int dk8 = (rem & 3) * 8;
            uint4 v = *(const uint4*)(ldsb + (y * 32 + di) * 64 + ((dk8 * 2) ^ ((di & 7) << 4)));
            const size_t fo = (size_t)(k0 >> 5) * 16384 + (size_t)((i0 + di) >> 4) * 512
                            + (size_t)(dk8 >> 3) * 128 + (di & 15) * 8;
            *(uint4*)(Xbf + (size_t)y * PLANE + fo) = v;
        }
    }
}

// ---------------------------------------------------------------------------
// Fused GEMM + C-contraction — R9 big-tile + K-SPLIT for 2 blocks/CU.
// R9 sized grid=256 at 1 block/CU "no tail" — which DISABLED m114's
// inter-block overlap: all 8 waves on a CU wait at the same vmcnt+barrier
// (R11 counters: 77% idle).  Fix: split K into 2 halves; grid = 512 =
// EXACTLY 2 co-resident blocks/CU (LDS 2x66.5 KB = 133 < 160 KB).  When
// block A drains at its barrier, block B's waves issue MFMA (m114: time =
// max, not sum).  Each block: 128x128 ij-tile x 2x2 xy x K=256 (8 k-steps,
// counted-vmcnt dbuf, fragment-layout staging, 0 bank conflicts), partial
// C-contraction atomically added (exact: sum splits over k).
// Cost: C read 2x (256 MB via L2 ~ +4 us aggregate) — bounded downside.
// ---------------------------------------------------------------------------
__global__ __launch_bounds__(512, 4) void gemm_kernel(const float* __restrict__ yp,
                                                      const unsigned short* __restrict__ Wbf,
                                                      const unsigned short* __restrict__ Xbf,
                                                      float* __restrict__ probs_acc) {
    __shared__ unsigned short S[2][32 * 512];   // dbuf x 32 fragment lines (64 KB)
    __shared__ float red[8][32];

    const int bid = blockIdx.x;
    const int xcd = bid & 7;
    const int local = bid >> 3;          // 0..63
    const int kh = local >> 5;           // 0..1  k-half
    const int tl = (local >> 4) & 1;     // 0..1
    const int group = local & 15;        // 0..15 xy-group
    const int i_t = xcd >> 1;                    // 0..3
    const int j_t = ((xcd & 1) << 1) | tl;       // 0..3
    const int i0 = i_t * 128, j0 = j_t * 128;
    const int x0 = (group >> 2) * 2, y0 = (group & 3) * 2;

    const int t = threadIdx.x;
    const int w = t >> 6;            // wave 0..7
    const int l = t & 63;
    const int wm = w >> 2, wn = w & 3;   // 2M x 4N wave grid
    const int lm = l & 15, quad = l >> 4;

    // staging: wave w copies fragment lines idx = w*4+q; k-half offset folded
    // into the base pointer (kh * 8 kc-chunks * 16384 elems).
    const size_t khofs = (size_t)kh * 8 * 16384;
    const unsigned short* gq[4];
    #pragma unroll
    for (int q = 0; q < 4; ++q) {
        const int idx = w * 4 + q;
        const int tile = idx >> 3;
        const int rt = idx & 7;
        if (tile < 2)
            gq[q] = Xbf + (size_t)(y0 + tile) * PLANE + (size_t)(i0 / 16 + rt) * 512
                  + khofs + l * 8;
        else
            gq[q] = Wbf + (size_t)(x0 + (tile - 2)) * PLANE + (size_t)(j0 / 16 + rt) * 512
                  + khofs + l * 8;
    }
    const int sbase = (w * 4) * 512;

    v4f acc[2][2][4][2];   // [dy][dx][mt][nt]
    #pragma unroll
    for (int a = 0; a < 2; ++a)
      #pragma unroll
      for (int bb = 0; bb < 2; ++bb)
        #pragma unroll
        for (int c = 0; c < 4; ++c)
          #pragma unroll
          for (int d = 0; d < 2; ++d)
            acc[a][bb][c][d] = (v4f){0.f, 0.f, 0.f, 0.f};

    // prologue: stage kc=0 -> buf0, kc=1 -> buf1; wait for buf0 only.
    #pragma unroll
    for (int q = 0; q < 4; ++q) async16(gq[q], &S[0][sbase + q * 512]);
    #pragma unroll
    for (int q = 0; q < 4; ++q) async16(gq[q] + 16384, &S[1][sbase + q * 512]);
    asm volatile("s_waitcnt vmcnt(4)" ::: "memory");
    bar();

    for (int kc = 0; kc < 8; ++kc) {
        const int cur = kc & 1;
        v8s aF[2][4], bF[2][2];
        #pragma unroll
        for (int dy = 0; dy < 2; ++dy)
            #pragma unroll
            for (int mt = 0; mt < 4; ++mt)
                aF[dy][mt] = *(const v8s*)&S[cur][(dy * 8 + wm * 4 + mt) * 512 + l * 8];
        #pragma unroll
        for (int dx = 0; dx < 2; ++dx)
            #pragma unroll
            for (int nt = 0; nt < 2; ++nt)
                bF[dx][nt] = *(const v8s*)&S[cur][((2 + dx) * 8 + wn * 2 + nt) * 512 + l * 8];
        __builtin_amdgcn_s_setprio(1);
        #pragma unroll
        for (int dy = 0; dy < 2; ++dy)
            #pragma unroll
            for (int dx = 0; dx < 2; ++dx)
                #pragma unroll
                for (int mt = 0; mt < 4; ++mt)
                    #pragma unroll
                    for (int nt = 0; nt < 2; ++nt)
                        acc[dy][dx][mt][nt] = __builtin_amdgcn_mfma_f32_16x16x32_bf16(
                            aF[dy][mt], bF[dx][nt], acc[dy][dx][mt][nt], 0, 0, 0);
        __builtin_amdgcn_s_setprio(0);
        bar();   // all waves done reading S[cur]
        if (kc + 2 < 8) {
            const size_t kb2 = (size_t)(kc + 2) * 16384;
            #pragma unroll
            for (int q = 0; q < 4; ++q) async16(gq[q] + kb2, &S[cur][sbase + q * 512]);
        }
        if (kc < 7) {
            if (kc + 2 < 8) asm volatile("s_waitcnt vmcnt(4)" ::: "memory");
            else            asm volatile("s_waitcnt vmcnt(0)" ::: "memory");
            bar();
        }
    }

    // ---- epilogue: contract 4 partial-T tiles with shared C[i,j,0..7] ----
    const float* Cp = yp + 3 * KD + 2 * (size_t)SZ;
    float zacc[2][2][8];
    #pragma unroll
    for (int dy = 0; dy < 2; ++dy)
      #pragma unroll
      for (int dx = 0; dx < 2; ++dx)
        #pragma unroll
        for (int z = 0; z < 8; ++z) zacc[dy][dx][z] = 0.f;

    #pragma unroll
    for (int mt = 0; mt < 4; ++mt) {
        #pragma unroll
        for (int nt = 0; nt < 2; ++nt) {
            #pragma unroll
            for (int r = 0; r < 4; ++r) {
                const int gi = i0 + wm * 64 + mt * 16 + quad * 4 + r;  // D row = i
                const int gj = j0 + wn * 32 + nt * 16 + lm;            // D col = j
                const float4* cp = (const float4*)(Cp + ((size_t)gi * KD + gj) * 8);
                const float4 c0 = cp[0], c1 = cp[1];
                #pragma unroll
                for (int dy = 0; dy < 2; ++dy) {
                    #pragma unroll
                    for (int dx = 0; dx < 2; ++dx) {
                        const float tv = acc[dy][dx][mt][nt][r];
                        zacc[dy][dx][0] += tv * c0.x; zacc[dy][dx][1] += tv * c0.y;
                        zacc[dy][dx][2] += tv * c0.z; zacc[dy][dx][3] += tv * c0.w;
                        zacc[dy][dx][4] += tv * c1.x; zacc[dy][dx][5] += tv * c1.y;
                        zacc[dy][dx][6] += tv * c1.z; zacc[dy][dx][7] += tv * c1.w;
                    }
                }
            }
        }
    }
    #pragma unroll
    for (int dy = 0; dy < 2; ++dy)
      #pragma unroll
      for (int dx = 0; dx < 2; ++dx)
        #pragma unroll
        for (int z = 0; z < 8; ++z) {
            float v = zacc[dy][dx][z];
            for (int off = 32; off > 0; off >>= 1)
                v += __shfl_xor(v, off, 64);
            zacc[dy][dx][z] = v;
        }
    if (l == 0) {
        #pragma unroll
        for (int dy = 0; dy < 2; ++dy)
          #pragma unroll
          for (int dx = 0; dx < 2; ++dx)
            #pragma unroll
            for (int z = 0; z < 8; ++z)
                red[w][(dy * 2 + dx) * 8 + z] = zacc[dy][dx][z];
    }
    __syncthreads();
    if (t < 32) {
        float s = 0.f;
        #pragma unroll
        for (int ww = 0; ww < 8; ++ww) s += red[ww][t];
        const int p = t >> 3;              // dy*2+dx
        const int dy = p >> 1, dx = p & 1, z = t & 7;
        atomicAdd(&probs_acc[((x0 + dx) * 8 + (y0 + dy)) * 8 + z], s);
    }
}

// ---------------------------------------------------------------------------
// Finalize: KL divergence + emit probs. out[0]=d, out[1..512]=probs.
// ---------------------------------------------------------------------------
__global__ __launch_bounds__(512) void finalize_kernel(const float* __restrict__ probs_acc,
                                                       const float* __restrict__ y_true,
                                                       float* __restrict__ out) {
    __shared__ float red[8];
    const int t = threadIdx.x;
    const float p = probs_acc[t];
    out[1 + t] = p;
    const float ytv = y_true[t];
    const float pc = fminf(fmaxf(p, 1e-10f), 1.0f);
    float term = ytv * (logf(ytv + 1e-10f) - logf(pc));
    for (int off = 32; off > 0; off >>= 1)
        term += __shfl_xor(term, off, 64);
    if ((t & 63) == 0) red[t >> 6] = term;
    __syncthreads();
    if (t == 0) {
        float s = 0.f;
        #pragma unroll
        for (int i = 0; i < 8; ++i) s += red[i];
        out[0] = s;
    }
}

extern "C" void kernel_launch(void* const* d_in, const int* in_sizes, int n_in,
                              void* d_out, int out_size, void* d_ws, size_t ws_size,
                              hipStream_t stream) {
    const float* yp = (const float*)d_in[0];
    const float* yt = (const float*)d_in[1];
    float* out = (float*)d_out;

    unsigned short* Wbf = (unsigned short*)d_ws;              // 8 planes: 4 MB
    unsigned short* Xbf = Wbf + (size_t)8 * PLANE;            // 8 planes: 4 MB
    float* probs_acc = (float*)(Xbf + (size_t)8 * PLANE);     // 512 floats

    pack_kernel<<<512, 256, 0, stream>>>(yp, Wbf, Xbf, probs_acc);
    gemm_kernel<<<512, 512, 0, stream>>>(yp, Wbf, Xbf, probs_acc);
    finalize_kernel<<<1, 512, 0, stream>>>(probs_acc, yt, out);
}

// Round 13
// 107.271 us; speedup vs baseline: 2.3909x; 2.3909x over previous
//
#include <hip/hip_runtime.h>
#include <hip/hip_bf16.h>
#include <stdint.h>

#define KD 512
#define OD 8
#define SZ (KD*KD*OD)       // 2097152 elements per tensor (A,B,C)
#define PLANE (KD*KD)       // 262144

typedef short v8s __attribute__((ext_vector_type(8)));
typedef float v4f __attribute__((ext_vector_type(4)));

#define GLOBAL_AS __attribute__((address_space(1)))
#define LDS_AS __attribute__((address_space(3)))

static __device__ __forceinline__ unsigned short f2bf(float f) {
    union { float f; unsigned int u; } v; v.f = f;
    unsigned int u = v.u;
    unsigned int r = u + 0x7FFF + ((u >> 16) & 1);   // RNE
    return (unsigned short)(r >> 16);
}

static __device__ __forceinline__ void async16(const unsigned short* g, unsigned short* l) {
    __builtin_amdgcn_global_load_lds((const GLOBAL_AS void*)g, (LDS_AS void*)l, 16, 0, 0);
}

static __device__ __forceinline__ void bar() {
    __builtin_amdgcn_sched_barrier(0);
    __builtin_amdgcn_s_barrier();
    __builtin_amdgcn_sched_barrier(0);
}

// ---------------------------------------------------------------------------
// FRAGMENT LAYOUT v2 (k-major, verified R6-R12): fragment (16 rows x 32 k)
// = 512 contiguous elems (1 KB):
//   elem_off = p*PLANE + (k>>5)*16384 + (r>>4)*512
//            + ((k>>3)&3)*128 + (r&15)*8 + (k&7)
// lane l owns elems [l*8, l*8+8) — the mfma_f32_16x16x32_bf16 operand map.
// ---------------------------------------------------------------------------

// ---------------------------------------------------------------------------
// Pack (R9 verbatim, passed 4x): A-pack emits full 1 KB fragment lines;
// B-pack transposes through swizzled LDS.  block 0 zeroes probs_acc.
// ---------------------------------------------------------------------------
__global__ __launch_bounds__(256) void pack_kernel(const float* __restrict__ yp,
                                                   unsigned short* __restrict__ Wbf,
                                                   unsigned short* __restrict__ Xbf,
                                                   float* __restrict__ probs_acc) {
    __shared__ unsigned short lds[8192];
    const float* Pa = yp;
    const float* Pb = yp + KD;
    const float* Pc = yp + 2 * KD;
    const float* A  = yp + 3 * KD;
    const float* B  = A + SZ;
    const int b = blockIdx.x;
    const int t = threadIdx.x;

    if (b == 0) { probs_acc[t] = 0.0f; probs_acc[t + 256] = 0.0f; }

    if (b < 256) {
        // ---- A-pack: jt = b>>3 (16 j), kb = b&7 (64 k) ----
        const int jt = b >> 3, kb = b & 7;
        const int j0 = jt * 16, k0 = kb * 64;
        #pragma unroll
        for (int cc = 0; cc < 2; ++cc) {
            const int cell = cc * 256 + t;
            const int kl = (cell & 31) * 2;
            const int jl = cell >> 5;
            const int j = j0 + jl, k = k0 + kl;
            const float pb = Pb[j];
            const float s0 = pb * Pc[k];
            const float s1 = pb * Pc[k + 1];
            const float4* src = (const float4*)(A + ((size_t)j * KD + k) * 8);
            float av[16];
            ((float4*)av)[0] = src[0];
            ((float4*)av)[1] = src[1];
            ((float4*)av)[2] = src[2];
            ((float4*)av)[3] = src[3];
            const int swz = (jl & 7) << 3;
            #pragma unroll
            for (int x = 0; x < 8; ++x) {
                ushort2 wv;
                wv.x = f2bf(av[x] * s0);
                wv.y = f2bf(av[8 + x] * s1);
                *(ushort2*)&lds[jl * 512 + x * 64 + (kl ^ swz)] = wv;
            }
        }
        __syncthreads();
        #pragma unroll
        for (int ss = 0; ss < 4; ++ss) {
            const int slot = ss * 256 + t;
            const int x = slot >> 7;
            const int kcc = (slot >> 6) & 1;
            const int l = slot & 63;
            const int jl = l & 15, kq = l >> 4;
            const int klocal = kcc * 32 + kq * 8;
            const int swz = (jl & 7) << 3;
            uint4 v = *(const uint4*)&lds[jl * 512 + x * 64 + (klocal ^ swz)];
            const size_t fo = (size_t)(kb * 2 + kcc) * 16384 + (size_t)jt * 512 + l * 8;
            *(uint4*)(Wbf + (size_t)x * PLANE + fo) = v;
        }
    } else {
        // ---- B-pack ----
        const int tb = b - 256;
        const int k0 = (tb / 16) * 32;
        const int i0 = (tb % 16) * 32;
        char* ldsb = (char*)lds;
        #pragma unroll
        for (int p = 0; p < 4; ++p) {
            const int idx = t + p * 256;
            const int dk = idx >> 5;
            const int di = idx & 31;
            const float pa = Pa[i0 + di];
            const float4* src = (const float4*)(B + ((size_t)(k0 + dk) * KD + (i0 + di)) * 8);
            float bv[8];
            ((float4*)bv)[0] = src[0];
            ((float4*)bv)[1] = src[1];
            const int swz = (di & 7) << 4;
            #pragma unroll
            for (int y = 0; y < 8; ++y)
                *(unsigned short*)(ldsb + (y * 32 + di) * 64 + ((dk * 2) ^ swz)) =
                    f2bf(bv[y] * pa);
        }
        __syncthreads();
        #pragma unroll
        for (int p = 0; p < 4; ++p) {
            const int c = t + p * 256;
            const int y = c >> 7;
            const int rem = c & 127;
            const int di = rem >> 2;
            const int dk8 = (rem & 3) * 8;
            uint4 v = *(const uint4*)(ldsb + (y * 32 + di) * 64 + ((dk8 * 2) ^ ((di & 7) << 4)));
            const size_t fo = (size_t)(k0 >> 5) * 16384 + (size_t)((i0 + di) >> 4) * 512
                            + (size_t)(dk8 >> 3) * 128 + (di & 15) * 8;
            *(uint4*)(Xbf + (size_t)y * PLANE + fo) = v;
        }
    }
}

// ---------------------------------------------------------------------------
// Fused GEMM + C-contraction — R9 big-tile + K-split, REGISTER BUDGET FIXED.
// R12's only change vs R8 was __launch_bounds__(512,4): VGPR cap 128 ->
// allocator squeezed to 64 and SPILLED the 128-VGPR accumulator (WRITE_SIZE
// 541 MB of scratch, 190 us).  Reverted to (512,2): R8 measured VGPR=120
// with this exact body — 4 waves/SIMD x 120 = 480 <= 512, LDS 2x66.5 =
// 133 <= 160 KB, so TWO blocks/CU co-reside without any spill.
// grid = 512 = 2 blocks/CU: the m114 inter-block overlap test, run properly
// — when block A drains at its vmcnt/barrier, block B's waves issue MFMA.
// Each block: 128x128 ij-tile x 2x2 xy x K=256 (8 k-steps, counted-vmcnt
// dbuf, fragment staging, 0 bank conflicts); partial contraction atomic-add
// (exact: the k-sum splits).  C re-read 2x stays in L2/L3 (no HBM cost).
// ---------------------------------------------------------------------------
__global__ __launch_bounds__(512, 2) void gemm_kernel(const float* __restrict__ yp,
                                                      const unsigned short* __restrict__ Wbf,
                                                      const unsigned short* __restrict__ Xbf,
                                                      float* __restrict__ probs_acc) {
    __shared__ unsigned short S[2][32 * 512];   // dbuf x 32 fragment lines (64 KB)
    __shared__ float red[8][32];

    const int bid = blockIdx.x;
    const int xcd = bid & 7;
    const int local = bid >> 3;          // 0..63
    const int kh = local >> 5;           // 0..1  k-half
    const int tl = (local >> 4) & 1;     // 0..1
    const int group = local & 15;        // 0..15 xy-group
    const int i_t = xcd >> 1;                    // 0..3
    const int j_t = ((xcd & 1) << 1) | tl;       // 0..3
    const int i0 = i_t * 128, j0 = j_t * 128;
    const int x0 = (group >> 2) * 2, y0 = (group & 3) * 2;

    const int t = threadIdx.x;
    const int w = t >> 6;            // wave 0..7
    const int l = t & 63;
    const int wm = w >> 2, wn = w & 3;   // 2M x 4N wave grid
    const int lm = l & 15, quad = l >> 4;

    // staging: wave w copies fragment lines idx = w*4+q; k-half folded into
    // the base pointer (kh * 8 kc-chunks * 16384 elems).
    const size_t khofs = (size_t)kh * 8 * 16384;
    const unsigned short* gq[4];
    #pragma unroll
    for (int q = 0; q < 4; ++q) {
        const int idx = w * 4 + q;
        const int tile = idx >> 3;
        const int rt = idx & 7;
        if (tile < 2)
            gq[q] = Xbf + (size_t)(y0 + tile) * PLANE + (size_t)(i0 / 16 + rt) * 512
                  + khofs + l * 8;
        else
            gq[q] = Wbf + (size_t)(x0 + (tile - 2)) * PLANE + (size_t)(j0 / 16 + rt) * 512
                  + khofs + l * 8;
    }
    const int sbase = (w * 4) * 512;

    v4f acc[2][2][4][2];   // [dy][dx][mt][nt]
    #pragma unroll
    for (int a = 0; a < 2; ++a)
      #pragma unroll
      for (int bb = 0; bb < 2; ++bb)
        #pragma unroll
        for (int c = 0; c < 4; ++c)
          #pragma unroll
          for (int d = 0; d < 2; ++d)
            acc[a][bb][c][d] = (v4f){0.f, 0.f, 0.f, 0.f};

    // prologue: stage kc=0 -> buf0, kc=1 -> buf1; wait for buf0 only.
    #pragma unroll
    for (int q = 0; q < 4; ++q) async16(gq[q], &S[0][sbase + q * 512]);
    #pragma unroll
    for (int q = 0; q < 4; ++q) async16(gq[q] + 16384, &S[1][sbase + q * 512]);
    asm volatile("s_waitcnt vmcnt(4)" ::: "memory");
    bar();

    for (int kc = 0; kc < 8; ++kc) {
        const int cur = kc & 1;
        v8s aF[2][4], bF[2][2];
        #pragma unroll
        for (int dy = 0; dy < 2; ++dy)
            #pragma unroll
            for (int mt = 0; mt < 4; ++mt)
                aF[dy][mt] = *(const v8s*)&S[cur][(dy * 8 + wm * 4 + mt) * 512 + l * 8];
        #pragma unroll
        for (int dx = 0; dx < 2; ++dx)
            #pragma unroll
            for (int nt = 0; nt < 2; ++nt)
                bF[dx][nt] = *(const v8s*)&S[cur][((2 + dx) * 8 + wn * 2 + nt) * 512 + l * 8];
        __builtin_amdgcn_s_setprio(1);
        #pragma unroll
        for (int dy = 0; dy < 2; ++dy)
            #pragma unroll
            for (int dx = 0; dx < 2; ++dx)
                #pragma unroll
                for (int mt = 0; mt < 4; ++mt)
                    #pragma unroll
                    for (int nt = 0; nt < 2; ++nt)
                        acc[dy][dx][mt][nt] = __builtin_amdgcn_mfma_f32_16x16x32_bf16(
                            aF[dy][mt], bF[dx][nt], acc[dy][dx][mt][nt], 0, 0, 0);
        __builtin_amdgcn_s_setprio(0);
        bar();   // all waves done reading S[cur]
        if (kc + 2 < 8) {
            const size_t kb2 = (size_t)(kc + 2) * 16384;
            #pragma unroll
            for (int q = 0; q < 4; ++q) async16(gq[q] + kb2, &S[cur][sbase + q * 512]);
        }
        if (kc < 7) {
            if (kc + 2 < 8) asm volatile("s_waitcnt vmcnt(4)" ::: "memory");
            else            asm volatile("s_waitcnt vmcnt(0)" ::: "memory");
            bar();
        }
    }

    // ---- epilogue: contract 4 partial-T tiles with shared C[i,j,0..7] ----
    const float* Cp = yp + 3 * KD + 2 * (size_t)SZ;
    float zacc[2][2][8];
    #pragma unroll
    for (int dy = 0; dy < 2; ++dy)
      #pragma unroll
      for (int dx = 0; dx < 2; ++dx)
        #pragma unroll
        for (int z = 0; z < 8; ++z) zacc[dy][dx][z] = 0.f;

    #pragma unroll
    for (int mt = 0; mt < 4; ++mt) {
        #pragma unroll
        for (int nt = 0; nt < 2; ++nt) {
            #pragma unroll
            for (int r = 0; r < 4; ++r) {
                const int gi = i0 + wm * 64 + mt * 16 + quad * 4 + r;  // D row = i
                const int gj = j0 + wn * 32 + nt * 16 + lm;            // D col = j
                const float4* cp = (const float4*)(Cp + ((size_t)gi * KD + gj) * 8);
                const float4 c0 = cp[0], c1 = cp[1];
                #pragma unroll
                for (int dy = 0; dy < 2; ++dy) {
                    #pragma unroll
                    for (int dx = 0; dx < 2; ++dx) {
                        const float tv = acc[dy][dx][mt][nt][r];
                        zacc[dy][dx][0] += tv * c0.x; zacc[dy][dx][1] += tv * c0.y;
                        zacc[dy][dx][2] += tv * c0.z; zacc[dy][dx][3] += tv * c0.w;
                        zacc[dy][dx][4] += tv * c1.x; zacc[dy][dx][5] += tv * c1.y;
                        zacc[dy][dx][6] += tv * c1.z; zacc[dy][dx][7] += tv * c1.w;
                    }
                }
            }
        }
    }
    #pragma unroll
    for (int dy = 0; dy < 2; ++dy)
      #pragma unroll
      for (int dx = 0; dx < 2; ++dx)
        #pragma unroll
        for (int z = 0; z < 8; ++z) {
            float v = zacc[dy][dx][z];
            for (int off = 32; off > 0; off >>= 1)
                v += __shfl_xor(v, off, 64);
            zacc[dy][dx][z] = v;
        }
    if (l == 0) {
        #pragma unroll
        for (int dy = 0; dy < 2; ++dy)
          #pragma unroll
          for (int dx = 0; dx < 2; ++dx)
            #pragma unroll
            for (int z = 0; z < 8; ++z)
                red[w][(dy * 2 + dx) * 8 + z] = zacc[dy][dx][z];
    }
    __syncthreads();
    if (t < 32) {
        float s = 0.f;
        #pragma unroll
        for (int ww = 0; ww < 8; ++ww) s += red[ww][t];
        const int p = t >> 3;              // dy*2+dx
        const int dy = p >> 1, dx = p & 1, z = t & 7;
        atomicAdd(&probs_acc[((x0 + dx) * 8 + (y0 + dy)) * 8 + z], s);
    }
}

// ---------------------------------------------------------------------------
// Finalize: KL divergence + emit probs. out[0]=d, out[1..512]=probs.
// ---------------------------------------------------------------------------
__global__ __launch_bounds__(512) void finalize_kernel(const float* __restrict__ probs_acc,
                                                       const float* __restrict__ y_true,
                                                       float* __restrict__ out) {
    __shared__ float red[8];
    const int t = threadIdx.x;
    const float p = probs_acc[t];
    out[1 + t] = p;
    const float ytv = y_true[t];
    const float pc = fminf(fmaxf(p, 1e-10f), 1.0f);
    float term = ytv * (logf(ytv + 1e-10f) - logf(pc));
    for (int off = 32; off > 0; off >>= 1)
        term += __shfl_xor(term, off, 64);
    if ((t & 63) == 0) red[t >> 6] = term;
    __syncthreads();
    if (t == 0) {
        float s = 0.f;
        #pragma unroll
        for (int i = 0; i < 8; ++i) s += red[i];
        out[0] = s;
    }
}

extern "C" void kernel_launch(void* const* d_in, const int* in_sizes, int n_in,
                              void* d_out, int out_size, void* d_ws, size_t ws_size,
                              hipStream_t stream) {
    const float* yp = (const float*)d_in[0];
    const float* yt = (const float*)d_in[1];
    float* out = (float*)d_out;

    unsigned short* Wbf = (unsigned short*)d_ws;              // 8 planes: 4 MB
    unsigned short* Xbf = Wbf + (size_t)8 * PLANE;            // 8 planes: 4 MB
    float* probs_acc = (float*)(Xbf + (size_t)8 * PLANE);     // 512 floats

    pack_kernel<<<512, 256, 0, stream>>>(yp, Wbf, Xbf, probs_acc);
    gemm_kernel<<<512, 512, 0, stream>>>(yp, Wbf, Xbf, probs_acc);
    finalize_kernel<<<1, 512, 0, stream>>>(probs_acc, yt, out);
}

// Round 14
// 98.913 us; speedup vs baseline: 2.5930x; 1.0845x over previous
//
#include <hip/hip_runtime.h>
#include <hip/hip_bf16.h>
#include <stdint.h>

#define KD 512
#define OD 8
#define SZ (KD*KD*OD)       // 2097152 elements per tensor (A,B,C)
#define PLANE (KD*KD)       // 262144

typedef short v8s __attribute__((ext_vector_type(8)));
typedef float v4f __attribute__((ext_vector_type(4)));

#define GLOBAL_AS __attribute__((address_space(1)))
#define LDS_AS __attribute__((address_space(3)))

static __device__ __forceinline__ unsigned short f2bf(float f) {
    union { float f; unsigned int u; } v; v.f = f;
    unsigned int u = v.u;
    unsigned int r = u + 0x7FFF + ((u >> 16) & 1);   // RNE
    return (unsigned short)(r >> 16);
}

static __device__ __forceinline__ void async16(const unsigned short* g, unsigned short* l) {
    __builtin_amdgcn_global_load_lds((const GLOBAL_AS void*)g, (LDS_AS void*)l, 16, 0, 0);
}

static __device__ __forceinline__ void bar() {
    __builtin_amdgcn_sched_barrier(0);
    __builtin_amdgcn_s_barrier();
    __builtin_amdgcn_sched_barrier(0);
}

// ---------------------------------------------------------------------------
// FRAGMENT LAYOUT v2 (k-major, verified R6-R13): fragment (16 rows x 32 k)
// = 512 contiguous elems (1 KB):
//   elem_off = p*PLANE + (k>>5)*16384 + (r>>4)*512
//            + ((k>>3)&3)*128 + (r&15)*8 + (k&7)
// lane l owns elems [l*8, l*8+8) — the mfma_f32_16x16x32_bf16 operand map.
// ---------------------------------------------------------------------------

// ---------------------------------------------------------------------------
// Pack (R9 verbatim, passed 5x): A-pack emits full 1 KB fragment lines;
// B-pack transposes through swizzled LDS.  block 0 zeroes probs_acc.
// ---------------------------------------------------------------------------
__global__ __launch_bounds__(256) void pack_kernel(const float* __restrict__ yp,
                                                   unsigned short* __restrict__ Wbf,
                                                   unsigned short* __restrict__ Xbf,
                                                   float* __restrict__ probs_acc) {
    __shared__ unsigned short lds[8192];
    const float* Pa = yp;
    const float* Pb = yp + KD;
    const float* Pc = yp + 2 * KD;
    const float* A  = yp + 3 * KD;
    const float* B  = A + SZ;
    const int b = blockIdx.x;
    const int t = threadIdx.x;

    if (b == 0) { probs_acc[t] = 0.0f; probs_acc[t + 256] = 0.0f; }

    if (b < 256) {
        // ---- A-pack: jt = b>>3 (16 j), kb = b&7 (64 k) ----
        const int jt = b >> 3, kb = b & 7;
        const int j0 = jt * 16, k0 = kb * 64;
        #pragma unroll
        for (int cc = 0; cc < 2; ++cc) {
            const int cell = cc * 256 + t;
            const int kl = (cell & 31) * 2;
            const int jl = cell >> 5;
            const int j = j0 + jl, k = k0 + kl;
            const float pb = Pb[j];
            const float s0 = pb * Pc[k];
            const float s1 = pb * Pc[k + 1];
            const float4* src = (const float4*)(A + ((size_t)j * KD + k) * 8);
            float av[16];
            ((float4*)av)[0] = src[0];
            ((float4*)av)[1] = src[1];
            ((float4*)av)[2] = src[2];
            ((float4*)av)[3] = src[3];
            const int swz = (jl & 7) << 3;
            #pragma unroll
            for (int x = 0; x < 8; ++x) {
                ushort2 wv;
                wv.x = f2bf(av[x] * s0);
                wv.y = f2bf(av[8 + x] * s1);
                *(ushort2*)&lds[jl * 512 + x * 64 + (kl ^ swz)] = wv;
            }
        }
        __syncthreads();
        #pragma unroll
        for (int ss = 0; ss < 4; ++ss) {
            const int slot = ss * 256 + t;
            const int x = slot >> 7;
            const int kcc = (slot >> 6) & 1;
            const int l = slot & 63;
            const int jl = l & 15, kq = l >> 4;
            const int klocal = kcc * 32 + kq * 8;
            const int swz = (jl & 7) << 3;
            uint4 v = *(const uint4*)&lds[jl * 512 + x * 64 + (klocal ^ swz)];
            const size_t fo = (size_t)(kb * 2 + kcc) * 16384 + (size_t)jt * 512 + l * 8;
            *(uint4*)(Wbf + (size_t)x * PLANE + fo) = v;
        }
    } else {
        // ---- B-pack ----
        const int tb = b - 256;
        const int k0 = (tb / 16) * 32;
        const int i0 = (tb % 16) * 32;
        char* ldsb = (char*)lds;
        #pragma unroll
        for (int p = 0; p < 4; ++p) {
            const int idx = t + p * 256;
            const int dk = idx >> 5;
            const int di = idx & 31;
            const float pa = Pa[i0 + di];
            const float4* src = (const float4*)(B + ((size_t)(k0 + dk) * KD + (i0 + di)) * 8);
            float bv[8];
            ((float4*)bv)[0] = src[0];
            ((float4*)bv)[1] = src[1];
            const int swz = (di & 7) << 4;
            #pragma unroll
            for (int y = 0; y < 8; ++y)
                *(unsigned short*)(ldsb + (y * 32 + di) * 64 + ((dk * 2) ^ swz)) =
                    f2bf(bv[y] * pa);
        }
        __syncthreads();
        #pragma unroll
        for (int p = 0; p < 4; ++p) {
            const int c = t + p * 256;
            const int y = c >> 7;
            const int rem = c & 127;
            const int di = rem >> 2;
            const int dk8 = (rem & 3) * 8;
            uint4 v = *(const uint4*)(ldsb + (y * 32 + di) * 64 + ((dk8 * 2) ^ ((di & 7) << 4)));
            const size_t fo = (size_t)(k0 >> 5) * 16384 + (size_t)((i0 + di) >> 4) * 512
                            + (size_t)(dk8 >> 3) * 128 + (di & 15) * 8;
            *(uint4*)(Xbf + (size_t)y * PLANE + fo) = v;
        }
    }
}

// ---------------------------------------------------------------------------
// Fused GEMM + C-contraction — R9 big-tile config RESTORED (best: 100.2 us).
// 128x128 ij-tile x 2x2 xy per block, 512 threads (8 waves, 2M x 4N),
// grid = 256.  Counted-vmcnt double buffer (vmcnt(4), never 0 mid-loop).
// XCD swizzle (per-XCD working set ~4 MB = one L2).  Fragment staging is
// linear -> global_load_lds legal, ds_read conflict-free (0 measured).
// ONE change vs R9: s_setprio REMOVED from the MFMA cluster — m190
// measured setprio as negative (-1.5%) on barrier-lockstep GEMMs (T5's
// prerequisite, per-phase wave role-diversity, is absent here).
//
// Session constraint note (R13 post-mortem): seven gemm structures all
// land ~40-45 us = ~430 TF effective on this 4096x4096x512-equivalent
// GEMM — inside the verified plain-HIP 2-phase band (m102: 320-833 TF at
// comparable FLOP).  The verified escape (256-sq 8-phase) forfeits the
// 4-way xy C-amortization (+~11 us serial L2 epilogue) and 8-phase@128-sq
// measured null (m232) — net non-positive for this problem's epilogue.
// ---------------------------------------------------------------------------
__global__ __launch_bounds__(512, 2) void gemm_kernel(const float* __restrict__ yp,
                                                      const unsigned short* __restrict__ Wbf,
                                                      const unsigned short* __restrict__ Xbf,
                                                      float* __restrict__ probs_acc) {
    __shared__ unsigned short S[2][32 * 512];   // dbuf x 32 fragment lines (64 KB)
    __shared__ float red[8][32];

    const int bid = blockIdx.x;
    const int xcd = bid & 7;
    const int local = bid >> 3;          // 0..31
    const int tl = local >> 4;           // 0..1
    const int group = local & 15;        // 0..15 xy-group
    const int i_t = xcd >> 1;                    // 0..3
    const int j_t = ((xcd & 1) << 1) | tl;       // 0..3
    const int i0 = i_t * 128, j0 = j_t * 128;
    const int x0 = (group >> 2) * 2, y0 = (group & 3) * 2;

    const int t = threadIdx.x;
    const int w = t >> 6;            // wave 0..7
    const int l = t & 63;
    const int wm = w >> 2, wn = w & 3;   // 2M x 4N wave grid
    const int lm = l & 15, quad = l >> 4;

    const unsigned short* gq[4];   // per-q staging source (lane-offset, kc=0)
    #pragma unroll
    for (int q = 0; q < 4; ++q) {
        const int idx = w * 4 + q;
        const int tile = idx >> 3;
        const int rt = idx & 7;
        if (tile < 2)
            gq[q] = Xbf + (size_t)(y0 + tile) * PLANE + (size_t)(i0 / 16 + rt) * 512 + l * 8;
        else
            gq[q] = Wbf + (size_t)(x0 + (tile - 2)) * PLANE + (size_t)(j0 / 16 + rt) * 512 + l * 8;
    }
    const int sbase = (w * 4) * 512;

    v4f acc[2][2][4][2];   // [dy][dx][mt][nt]
    #pragma unroll
    for (int a = 0; a < 2; ++a)
      #pragma unroll
      for (int bb = 0; bb < 2; ++bb)
        #pragma unroll
        for (int c = 0; c < 4; ++c)
          #pragma unroll
          for (int d = 0; d < 2; ++d)
            acc[a][bb][c][d] = (v4f){0.f, 0.f, 0.f, 0.f};

    #pragma unroll
    for (int q = 0; q < 4; ++q) async16(gq[q], &S[0][sbase + q * 512]);
    #pragma unroll
    for (int q = 0; q < 4; ++q) async16(gq[q] + 16384, &S[1][sbase + q * 512]);
    asm volatile("s_waitcnt vmcnt(4)" ::: "memory");
    bar();

    for (int kc = 0; kc < 16; ++kc) {
        const int cur = kc & 1;
        v8s aF[2][4], bF[2][2];
        #pragma unroll
        for (int dy = 0; dy < 2; ++dy)
            #pragma unroll
            for (int mt = 0; mt < 4; ++mt)
                aF[dy][mt] = *(const v8s*)&S[cur][(dy * 8 + wm * 4 + mt) * 512 + l * 8];
        #pragma unroll
        for (int dx = 0; dx < 2; ++dx)
            #pragma unroll
            for (int nt = 0; nt < 2; ++nt)
                bF[dx][nt] = *(const v8s*)&S[cur][((2 + dx) * 8 + wn * 2 + nt) * 512 + l * 8];
        #pragma unroll
        for (int dy = 0; dy < 2; ++dy)
            #pragma unroll
            for (int dx = 0; dx < 2; ++dx)
                #pragma unroll
                for (int mt = 0; mt < 4; ++mt)
                    #pragma unroll
                    for (int nt = 0; nt < 2; ++nt)
                        acc[dy][dx][mt][nt] = __builtin_amdgcn_mfma_f32_16x16x32_bf16(
                            aF[dy][mt], bF[dx][nt], acc[dy][dx][mt][nt], 0, 0, 0);
        bar();   // all waves done reading S[cur]
        if (kc + 2 < 16) {
            const size_t kb2 = (size_t)(kc + 2) * 16384;
            #pragma unroll
            for (int q = 0; q < 4; ++q) async16(gq[q] + kb2, &S[cur][sbase + q * 512]);
        }
        if (kc < 15) {
            if (kc + 2 < 16) asm volatile("s_waitcnt vmcnt(4)" ::: "memory");
            else             asm volatile("s_waitcnt vmcnt(0)" ::: "memory");
            bar();
        }
    }

    // ---- epilogue: contract 4 T tiles with shared C[i,j,0..7] (fp32, L2) ----
    const float* Cp = yp + 3 * KD + 2 * (size_t)SZ;
    float zacc[2][2][8];
    #pragma unroll
    for (int dy = 0; dy < 2; ++dy)
      #pragma unroll
      for (int dx = 0; dx < 2; ++dx)
        #pragma unroll
        for (int z = 0; z < 8; ++z) zacc[dy][dx][z] = 0.f;

    #pragma unroll
    for (int mt = 0; mt < 4; ++mt) {
        #pragma unroll
        for (int nt = 0; nt < 2; ++nt) {
            #pragma unroll
            for (int r = 0; r < 4; ++r) {
                const int gi = i0 + wm * 64 + mt * 16 + quad * 4 + r;  // D row = i
                const int gj = j0 + wn * 32 + nt * 16 + lm;            // D col = j
                const float4* cp = (const float4*)(Cp + ((size_t)gi * KD + gj) * 8);
                const float4 c0 = cp[0], c1 = cp[1];
                #pragma unroll
                for (int dy = 0; dy < 2; ++dy) {
                    #pragma unroll
                    for (int dx = 0; dx < 2; ++dx) {
                        const float tv = acc[dy][dx][mt][nt][r];
                        zacc[dy][dx][0] += tv * c0.x; zacc[dy][dx][1] += tv * c0.y;
                        zacc[dy][dx][2] += tv * c0.z; zacc[dy][dx][3] += tv * c0.w;
                        zacc[dy][dx][4] += tv * c1.x; zacc[dy][dx][5] += tv * c1.y;
                        zacc[dy][dx][6] += tv * c1.z; zacc[dy][dx][7] += tv * c1.w;
                    }
                }
            }
        }
    }
    #pragma unroll
    for (int dy = 0; dy < 2; ++dy)
      #pragma unroll
      for (int dx = 0; dx < 2; ++dx)
        #pragma unroll
        for (int z = 0; z < 8; ++z) {
            float v = zacc[dy][dx][z];
            for (int off = 32; off > 0; off >>= 1)
                v += __shfl_xor(v, off, 64);
            zacc[dy][dx][z] = v;
        }
    if (l == 0) {
        #pragma unroll
        for (int dy = 0; dy < 2; ++dy)
          #pragma unroll
          for (int dx = 0; dx < 2; ++dx)
            #pragma unroll
            for (int z = 0; z < 8; ++z)
                red[w][(dy * 2 + dx) * 8 + z] = zacc[dy][dx][z];
    }
    __syncthreads();
    if (t < 32) {
        float s = 0.f;
        #pragma unroll
        for (int ww = 0; ww < 8; ++ww) s += red[ww][t];
        const int p = t >> 3;              // dy*2+dx
        const int dy = p >> 1, dx = p & 1, z = t & 7;
        atomicAdd(&probs_acc[((x0 + dx) * 8 + (y0 + dy)) * 8 + z], s);
    }
}

// ---------------------------------------------------------------------------
// Finalize: KL divergence + emit probs. out[0]=d, out[1..512]=probs.
// ---------------------------------------------------------------------------
__global__ __launch_bounds__(512) void finalize_kernel(const float* __restrict__ probs_acc,
                                                       const float* __restrict__ y_true,
                                                       float* __restrict__ out) {
    __shared__ float red[8];
    const int t = threadIdx.x;
    const float p = probs_acc[t];
    out[1 + t] = p;
    const float ytv = y_true[t];
    const float pc = fminf(fmaxf(p, 1e-10f), 1.0f);
    float term = ytv * (logf(ytv + 1e-10f) - logf(pc));
    for (int off = 32; off > 0; off >>= 1)
        term += __shfl_xor(term, off, 64);
    if ((t & 63) == 0) red[t >> 6] = term;
    __syncthreads();
    if (t == 0) {
        float s = 0.f;
        #pragma unroll
        for (int i = 0; i < 8; ++i) s += red[i];
        out[0] = s;
    }
}

extern "C" void kernel_launch(void* const* d_in, const int* in_sizes, int n_in,
                              void* d_out, int out_size, void* d_ws, size_t ws_size,
                              hipStream_t stream) {
    const float* yp = (const float*)d_in[0];
    const float* yt = (const float*)d_in[1];
    float* out = (float*)d_out;

    unsigned short* Wbf = (unsigned short*)d_ws;              // 8 planes: 4 MB
    unsigned short* Xbf = Wbf + (size_t)8 * PLANE;            // 8 planes: 4 MB
    float* probs_acc = (float*)(Xbf + (size_t)8 * PLANE);     // 512 floats

    pack_kernel<<<512, 256, 0, stream>>>(yp, Wbf, Xbf, probs_acc);
    gemm_kernel<<<256, 512, 0, stream>>>(yp, Wbf, Xbf, probs_acc);
    finalize_kernel<<<1, 512, 0, stream>>>(probs_acc, yt, out);
}